// Round 2
// baseline (930.994 us; speedup 1.0000x reference)
//
#include <hip/hip_runtime.h>
#include <cstdint>

typedef unsigned short u16;
typedef short short8 __attribute__((ext_vector_type(8)));
typedef float f32x4 __attribute__((ext_vector_type(4)));

#define D_DIM 192
#define M_PROT 128
#define KCOLS 256
#define TILES 16
#define KSTEPS 6
#define GRID_P 256
#define BLK 512
#define LDSLO_TILES 8
// LDS chunks (16B): phi = 256 rows * 24 chunks = 6144 ; plo(local 128 rows) = 3072 ; colacc after
#define LDS_COLACC_BYTES 147456
#define SMEM_BYTES 148480

__device__ __forceinline__ float newton_rsqrt(float ss) {
    float m = fmaxf(ss, 1e-12f);
    float r = rsqrtf(m);
    r = r * (1.5f - 0.5f * m * r * r);   // refine to ~fp32 exact
    return r;
}

// split fp32 -> bf16 hi (RNE) + bf16 lo (trunc of exact residual)
__device__ __forceinline__ void split1(float f, uint32_t& h, uint32_t& l) {
    uint32_t u = __float_as_uint(f);
    uint32_t uh = (u + 0x7FFFu + ((u >> 16) & 1u)) & 0xFFFF0000u;
    h = uh >> 16;
    l = __float_as_uint(f - __uint_as_float(uh)) >> 16;
}

// ---------------------------------------------------------------------------
// per-proto: bf16 hi/lo arrays, exact fp32 inv-norm, lastIdx init
__global__ void prep_kern(const float* __restrict__ lp, const float* __restrict__ gp,
                          u16* __restrict__ phi, u16* __restrict__ plo,
                          float* __restrict__ invnp, int* __restrict__ lastIdx) {
    int r = blockIdx.x, j = threadIdx.x;  // 256 blocks x 64 threads
    const float* src = (r < M_PROT) ? (lp + r * D_DIM) : (gp + (r - M_PROT) * D_DIM);
    float ss = 0.0f;
    for (int c = j; c < D_DIM; c += 64) {
        float f = src[c];
        ss = fmaf(f, f, ss);
        uint32_t h, l;
        split1(f, h, l);
        phi[r * D_DIM + c] = (u16)h;
        plo[r * D_DIM + c] = (u16)l;
    }
#pragma unroll
    for (int m = 1; m <= 32; m <<= 1) ss += __shfl_xor(ss, m);
    if (j == 0) {
        invnp[r] = newton_rsqrt(ss);
        if (r < M_PROT) lastIdx[r] = -1;
    }
}

// ---------------------------------------------------------------------------
// gated[m][j] = lin[j]*sigmoid(lin[j+192]),  lin = gp[m]@W + b   (fp32)
__global__ __launch_bounds__(384) void glu_kern(const float* __restrict__ gp,
                                                const float* __restrict__ W,
                                                const float* __restrict__ b,
                                                float* __restrict__ gated) {
    __shared__ float grow[D_DIM];
    __shared__ float lin[2 * D_DIM];
    int m = blockIdx.x, j = threadIdx.x;
    if (j < D_DIM) grow[j] = gp[m * D_DIM + j];
    __syncthreads();
    float a = b[j];
    for (int k = 0; k < D_DIM; k++) a = fmaf(grow[k], W[k * 2 * D_DIM + j], a);
    lin[j] = a;
    __syncthreads();
    if (j < D_DIM) {
        float g = lin[j] * (1.0f / (1.0f + __expf(-lin[j + D_DIM])));
        gated[m * D_DIM + j] = g;
    }
}

// ---------------------------------------------------------------------------
// out_j = 1 / sum_g partials[g][j]   (chained factors absorb constants)
__global__ void reduce_cols(const float* __restrict__ partials, float* __restrict__ outf, int G) {
    int j = threadIdx.x;  // 256 threads, 1 block
    float s = 0.0f;
    for (int g = 0; g < G; g++) s += partials[g * KCOLS + j];
    outf[j] = 1.0f / s;
}

// ---------------------------------------------------------------------------
template <int PASS>
__global__ __launch_bounds__(BLK, 2) void pass_kern(
    const float* __restrict__ x, const u16* __restrict__ phi_g, const u16* __restrict__ plo_g,
    const float* __restrict__ invnp, const float* __restrict__ colfac,
    float* __restrict__ partials, int* __restrict__ lastIdx,
    const float* __restrict__ gated, float* __restrict__ outp, int nrows) {
    extern __shared__ char smem[];
    uint4* ldsv = (uint4*)smem;
    float* colacc = (float*)(smem + LDS_COLACC_BYTES);

    const int tid = threadIdx.x;
    const uint4* phiv = (const uint4*)phi_g;
    const uint4* plov = (const uint4*)plo_g;
    // stage: phi all 256 rows (chunks 0..6143), plo local 128 rows (chunks 6144..9215)
    for (int idx = tid; idx < 9216; idx += BLK) {
        if (idx < 6144) {
            int r = idx / 24, c = idx - r * 24;
            ldsv[r * 24 + (c ^ (r & 7))] = phiv[idx];
        } else {
            int k = idx - 6144;
            int r = k / 24, c = k - r * 24;
            ldsv[6144 + r * 24 + (c ^ (r & 7))] = plov[k];
        }
    }
    if (tid < KCOLS) colacc[tid] = 0.0f;
    __syncthreads();

    const int lane = tid & 63;
    const int wave = tid >> 6;
    const int quad = lane >> 4;
    const int lcol = lane & 15;
    const int swz = lcol & 7;

    float pnf[TILES];
    float cf[TILES];
#pragma unroll
    for (int t = 0; t < TILES; t++) {
        pnf[t] = invnp[t * 16 + lcol];
        if constexpr (PASS >= 2) cf[t] = colfac[t * 16 + lcol];
    }

    float colpart[TILES];
#pragma unroll
    for (int t = 0; t < TILES; t++) colpart[t] = 0.0f;

    const int ntiles = nrows >> 7;  // 128 rows per tile (8 waves x 16)
    for (int tile = blockIdx.x; tile < ntiles; tile += gridDim.x) {
        const int rowbase = tile * 128 + wave * 16;
        const float* xp = x + (size_t)(rowbase + lcol) * D_DIM + quad * 8;

        f32x4 acc[TILES];
        f32x4 zero = {};
#pragma unroll
        for (int t = 0; t < TILES; t++) acc[t] = zero;
        float ssq = 0.0f;

#pragma unroll 1
        for (int kk = 0; kk < KSTEPS; kk++) {
            float4 f0 = *(const float4*)(xp + kk * 32);
            float4 f1 = *(const float4*)(xp + kk * 32 + 4);
            float fv[8] = {f0.x, f0.y, f0.z, f0.w, f1.x, f1.y, f1.z, f1.w};
            uint32_t hp[4], lq[4];
#pragma unroll
            for (int i = 0; i < 4; i++) {
                uint32_t h0, l0, h1, l1;
                split1(fv[2 * i], h0, l0);
                split1(fv[2 * i + 1], h1, l1);
                ssq = fmaf(fv[2 * i], fv[2 * i], ssq);
                ssq = fmaf(fv[2 * i + 1], fv[2 * i + 1], ssq);
                hp[i] = h0 | (h1 << 16);
                lq[i] = l0 | (l1 << 16);
            }
            uint4 hraw = {hp[0], hp[1], hp[2], hp[3]};
            uint4 lraw = {lq[0], lq[1], lq[2], lq[3]};
            short8 xhi = __builtin_bit_cast(short8, hraw);
            short8 xlo = __builtin_bit_cast(short8, lraw);
            const int ckk = kk * 4 + quad;       // global chunk index within row
            const int cswz = ckk ^ swz;          // LDS-swizzled chunk index
#pragma unroll
            for (int t = 0; t < TILES; t++) {
                const int row = t * 16 + lcol;
                uint4 braw = ldsv[row * 24 + cswz];
                short8 bhi = __builtin_bit_cast(short8, braw);
                uint4 braw2;
                if (t < LDSLO_TILES) braw2 = ldsv[6144 + row * 24 + cswz];
                else braw2 = plov[row * 24 + ckk];
                short8 blo = __builtin_bit_cast(short8, braw2);
                acc[t] = __builtin_amdgcn_mfma_f32_16x16x32_bf16(xhi, bhi, acc[t], 0, 0, 0);
                acc[t] = __builtin_amdgcn_mfma_f32_16x16x32_bf16(xhi, blo, acc[t], 0, 0, 0);
                acc[t] = __builtin_amdgcn_mfma_f32_16x16x32_bf16(xlo, bhi, acc[t], 0, 0, 0);
            }
        }

        // exact row inv-norm: lane's ssq covers row lcol's k-chunks; fold quads
        ssq += __shfl_xor(ssq, 16);
        ssq += __shfl_xor(ssq, 32);
        float invnx = newton_rsqrt(ssq);
        float invnxr[4];  // redistribute to C/D row layout: row = quad*4 + r
#pragma unroll
        for (int r = 0; r < 4; r++) invnxr[r] = __shfl(invnx, quad * 4 + r);

        // E = exp(sim / 0.05)
#pragma unroll
        for (int t = 0; t < TILES; t++) {
#pragma unroll
            for (int r = 0; r < 4; r++) {
                float sim = acc[t][r] * invnxr[r] * pnf[t];
                acc[t][r] = __expf(sim * 20.0f);
            }
        }

        if constexpr (PASS <= 3) {
            float rinv[4];
#pragma unroll
            for (int r = 0; r < 4; r++) {
                float a = 0.0f;
#pragma unroll
                for (int t = 0; t < TILES; t++) {
                    if constexpr (PASS == 1) a += acc[t][r];
                    else a += acc[t][r] * cf[t];
                }
                a += __shfl_xor(a, 1);
                a += __shfl_xor(a, 2);
                a += __shfl_xor(a, 4);
                a += __shfl_xor(a, 8);
                rinv[r] = 1.0f / a;
            }
#pragma unroll
            for (int t = 0; t < TILES; t++) {
                colpart[t] += acc[t][0] * rinv[0] + acc[t][1] * rinv[1] +
                              acc[t][2] * rinv[2] + acc[t][3] * rinv[3];
            }
        } else {
            // PASS 4: per-row argmax of E*g3 over each half (first-max tiebreak)
            float bvL[4], bvG[4];
            int biL[4], biG[4];
#pragma unroll
            for (int r = 0; r < 4; r++) { bvL[r] = -1.0f; biL[r] = 0; bvG[r] = -1.0f; biG[r] = 0; }
#pragma unroll
            for (int t = 0; t < TILES; t++) {
                float fc = cf[t];
                int col = (t & 7) * 16 + lcol;
#pragma unroll
                for (int r = 0; r < 4; r++) {
                    float v = acc[t][r] * fc;
                    if (t < 8) { if (v > bvL[r]) { bvL[r] = v; biL[r] = col; } }
                    else       { if (v > bvG[r]) { bvG[r] = v; biG[r] = col; } }
                }
            }
#pragma unroll
            for (int r = 0; r < 4; r++) {
#pragma unroll
                for (int m = 1; m <= 8; m <<= 1) {
                    float ov = __shfl_xor(bvL[r], m);
                    int oi = __shfl_xor(biL[r], m);
                    if (ov > bvL[r] || (ov == bvL[r] && oi < biL[r])) { bvL[r] = ov; biL[r] = oi; }
                    ov = __shfl_xor(bvG[r], m);
                    oi = __shfl_xor(biG[r], m);
                    if (ov > bvG[r] || (ov == bvG[r] && oi < biG[r])) { bvG[r] = ov; biG[r] = oi; }
                }
            }
            if (lcol == 0) {
#pragma unroll
                for (int r = 0; r < 4; r++) atomicMax(&lastIdx[biL[r]], rowbase + quad * 4 + r);
            }
            // epilogue: out = l2norm(0.5*gated[ga] + 0.5*x), wave-private rows
            for (int rr = 0; rr < 16; rr++) {
                int growi = rowbase + rr;
                int ga = __shfl(biG[rr & 3], (rr >> 2) * 16);
                const float* gr = gated + ga * D_DIM;
                const float* xr = x + (size_t)growi * D_DIM;
                float v0 = 0.5f * gr[lane] + 0.5f * xr[lane];
                float v1 = 0.5f * gr[lane + 64] + 0.5f * xr[lane + 64];
                float v2 = 0.5f * gr[lane + 128] + 0.5f * xr[lane + 128];
                float ss = v0 * v0 + v1 * v1 + v2 * v2;
                ss += __shfl_xor(ss, 1);
                ss += __shfl_xor(ss, 2);
                ss += __shfl_xor(ss, 4);
                ss += __shfl_xor(ss, 8);
                ss += __shfl_xor(ss, 16);
                ss += __shfl_xor(ss, 32);
                float sc = newton_rsqrt(ss);
                float* orow = outp + (size_t)growi * D_DIM;
                orow[lane] = v0 * sc;
                orow[lane + 64] = v1 * sc;
                orow[lane + 128] = v2 * sc;
            }
        }
    }

    if constexpr (PASS <= 3) {
#pragma unroll
        for (int t = 0; t < TILES; t++) {
            float c = colpart[t];
            c += __shfl_xor(c, 16);
            c += __shfl_xor(c, 32);
            if (quad == 0) atomicAdd(&colacc[t * 16 + lcol], c);
        }
        __syncthreads();
        if (tid < KCOLS) partials[blockIdx.x * KCOLS + tid] = colacc[tid];
    }
}

// ---------------------------------------------------------------------------
// new_local[m] = assigned ? 0.96*lp[m] + 0.04*x[lastIdx[m]] : lp[m]
__global__ void final_local(const float* __restrict__ lp, const float* __restrict__ x,
                            const int* __restrict__ lastIdx, float* __restrict__ outL) {
    int m = blockIdx.x;   // 128
    int c = threadIdx.x;  // 192
    int idx = lastIdx[m];
    float v = lp[m * D_DIM + c];
    if (idx >= 0) v = 0.96f * v + (float)(1.0 - 0.96) * x[(size_t)idx * D_DIM + c];
    outL[m * D_DIM + c] = v;
}

// ---------------------------------------------------------------------------
extern "C" void kernel_launch(void* const* d_in, const int* in_sizes, int n_in,
                              void* d_out, int out_size, void* d_ws, size_t ws_size,
                              hipStream_t stream) {
    const float* x = (const float*)d_in[0];
    const float* lp = (const float*)d_in[1];
    const float* gp = (const float*)d_in[2];
    const float* W = (const float*)d_in[3];
    const float* b = (const float*)d_in[4];
    float* out = (float*)d_out;
    const int nrows = in_sizes[0] / D_DIM;  // 131072

    char* wsb = (char*)d_ws;
    float* invnp = (float*)(wsb + 0);        // 256 f
    float* g1 = (float*)(wsb + 1024);        // 256 f
    float* g2 = (float*)(wsb + 2048);        // 256 f
    float* g3 = (float*)(wsb + 3072);        // 256 f
    int* lastIdx = (int*)(wsb + 4096);       // 128 i
    float* gated = (float*)(wsb + 8192);     // 128*192 f = 98304 B
    u16* phi = (u16*)(wsb + 106496);         // 256*192 u16 = 98304 B
    u16* plo = (u16*)(wsb + 204800);         // 256*192 u16 = 98304 B
    float* partials = (float*)(wsb + 303104);// 256*256 f = 262144 B

    prep_kern<<<256, 64, 0, stream>>>(lp, gp, phi, plo, invnp, lastIdx);
    glu_kern<<<128, 384, 0, stream>>>(gp, W, b, gated);
    pass_kern<1><<<GRID_P, BLK, SMEM_BYTES, stream>>>(x, phi, plo, invnp, nullptr, partials,
                                                      nullptr, nullptr, nullptr, nrows);
    reduce_cols<<<1, 256, 0, stream>>>(partials, g1, GRID_P);
    pass_kern<2><<<GRID_P, BLK, SMEM_BYTES, stream>>>(x, phi, plo, invnp, g1, partials,
                                                      nullptr, nullptr, nullptr, nrows);
    reduce_cols<<<1, 256, 0, stream>>>(partials, g2, GRID_P);
    pass_kern<3><<<GRID_P, BLK, SMEM_BYTES, stream>>>(x, phi, plo, invnp, g2, partials,
                                                      nullptr, nullptr, nullptr, nrows);
    reduce_cols<<<1, 256, 0, stream>>>(partials, g3, GRID_P);
    pass_kern<4><<<GRID_P, BLK, SMEM_BYTES, stream>>>(x, phi, plo, invnp, g3, nullptr,
                                                      lastIdx, gated, out, nrows);
    final_local<<<128, 192, 0, stream>>>(lp, x, lastIdx, out + (size_t)nrows * D_DIM);
}

// Round 3
// 750.222 us; speedup vs baseline: 1.2410x; 1.2410x over previous
//
#include <hip/hip_runtime.h>
#include <cstdint>

typedef unsigned short u16;
typedef unsigned long long u64;
typedef short short8 __attribute__((ext_vector_type(8)));
typedef float f32x4 __attribute__((ext_vector_type(4)));

#define D_DIM 192
#define M_PROT 128
#define KCOLS 256
#define GRID_P 256
#define BLK 512
#define CHUNK_ROWS 64
#define XSTRIDE 200   // u16 per x-row in LDS; 100 dwords -> lcol*4-mod-32 banks, 2-way, free

__device__ __forceinline__ float newton_rsqrt(float ss) {
    float m = fmaxf(ss, 1e-12f);
    float r = rsqrtf(m);
    r = r * (1.5f - 0.5f * m * r * r);
    return r;
}
__device__ __forceinline__ float fast_rcp(float x) {
    float r = __builtin_amdgcn_rcpf(x);
    return r * (2.0f - x * r);   // 1 NR -> ~1e-7 rel
}
__device__ __forceinline__ float bf2f(u16 u) {
    return __uint_as_float(((uint32_t)u) << 16);
}
// split fp32 -> bf16 hi (RNE) + bf16 lo (trunc of exact residual)
__device__ __forceinline__ void split1(float f, uint32_t& h, uint32_t& l) {
    uint32_t u = __float_as_uint(f);
    uint32_t uh = (u + 0x7FFFu + ((u >> 16) & 1u)) & 0xFFFF0000u;
    h = uh >> 16;
    l = __float_as_uint(f - __uint_as_float(uh)) >> 16;
}

// ---------------------------------------------------------------------------
__global__ void prep_kern(const float* __restrict__ lp, const float* __restrict__ gp,
                          u16* __restrict__ phi, u16* __restrict__ plo,
                          float* __restrict__ invnp, int* __restrict__ lastIdx) {
    int r = blockIdx.x, j = threadIdx.x;  // 256 x 64
    const float* src = (r < M_PROT) ? (lp + r * D_DIM) : (gp + (r - M_PROT) * D_DIM);
    float ss = 0.0f;
    for (int c = j; c < D_DIM; c += 64) {
        float f = src[c];
        ss = fmaf(f, f, ss);
        uint32_t h, l;
        split1(f, h, l);
        phi[r * D_DIM + c] = (u16)h;
        plo[r * D_DIM + c] = (u16)l;
    }
#pragma unroll
    for (int m = 1; m <= 32; m <<= 1) ss += __shfl_xor(ss, m);
    if (j == 0) {
        invnp[r] = newton_rsqrt(ss);
        if (r < M_PROT) lastIdx[r] = -1;
    }
}

// ---------------------------------------------------------------------------
__global__ __launch_bounds__(384) void glu_kern(const float* __restrict__ gp,
                                                const float* __restrict__ W,
                                                const float* __restrict__ b,
                                                float* __restrict__ gated) {
    __shared__ float grow[D_DIM];
    __shared__ float lin[2 * D_DIM];
    int m = blockIdx.x, j = threadIdx.x;
    if (j < D_DIM) grow[j] = gp[m * D_DIM + j];
    __syncthreads();
    float a = b[j];
    for (int k = 0; k < D_DIM; k++) a = fmaf(grow[k], W[k * 2 * D_DIM + j], a);
    lin[j] = a;
    __syncthreads();
    if (j < D_DIM) {
        float g = lin[j] * (1.0f / (1.0f + __expf(-lin[j + D_DIM])));
        gated[m * D_DIM + j] = g;
    }
}

// ---------------------------------------------------------------------------
__global__ void reduce_cols(const float* __restrict__ partials, float* __restrict__ outf, int G) {
    int j = threadIdx.x;
    float s = 0.0f;
    for (int g = 0; g < G; g++) s += partials[g * KCOLS + j];
    outf[j] = 1.0f / s;
}

// ---------------------------------------------------------------------------
// B(protos hi/lo) in registers per wave (32 cols), x staged in LDS per 64-row
// chunk with reg-prefetch. PASS 1-3: sinkhorn column partials; PASS 4: argmax
// + epilogue.
template <int PASS>
__global__ __launch_bounds__(BLK, 2) void pass_kern(
    const float* __restrict__ x, const uint4* __restrict__ phiv, const uint4* __restrict__ plov,
    const float* __restrict__ invnp, const float* __restrict__ colfac,
    float* __restrict__ partials, int* __restrict__ lastIdx,
    const float* __restrict__ gated, float* __restrict__ outp, int nchunks) {
    __shared__ u16 xhiS[CHUNK_ROWS * XSTRIDE];
    __shared__ u16 xloS[CHUNK_ROWS * XSTRIDE];
    __shared__ float xss[CHUNK_ROWS];
    __shared__ float rsum[CHUNK_ROWS];
    __shared__ u64 bestL[CHUNK_ROWS];
    __shared__ u64 bestG[CHUNK_ROWS];

    const int tid = threadIdx.x;
    const int lane = tid & 63;
    const int wave = tid >> 6;
    const int quad = lane >> 4;
    const int lcol = lane & 15;
    const int c0 = wave * 32;

    // --- B fragments in registers: wave's 32 proto cols, all K, hi+lo ---
    uint4 Bhi[2][6], Blo[2][6];
#pragma unroll
    for (int t = 0; t < 2; t++) {
        int prow = c0 + t * 16 + lcol;
#pragma unroll
        for (int kk = 0; kk < 6; kk++) {
            int idx = prow * 24 + kk * 4 + quad;
            Bhi[t][kk] = phiv[idx];
            Blo[t][kk] = plov[idx];
        }
    }
    float pnf[2], cf[2];
#pragma unroll
    for (int t = 0; t < 2; t++) {
        pnf[t] = invnp[c0 + t * 16 + lcol];
        if constexpr (PASS >= 2) cf[t] = colfac[c0 + t * 16 + lcol];
        else cf[t] = 1.0f;
    }
    float colpart[2] = {0.0f, 0.0f};

    // prefetch chunk 0
    float4 st[6];
    int chunk = blockIdx.x;
    if (chunk < nchunks) {
        const float4* src = (const float4*)(x + (size_t)chunk * CHUNK_ROWS * D_DIM);
#pragma unroll
        for (int i = 0; i < 6; i++) st[i] = src[tid + BLK * i];
    }

    for (; chunk < nchunks; chunk += gridDim.x) {
        __syncthreads();  // S0: previous chunk's consumers done
        if (tid < CHUNK_ROWS) {
            xss[tid] = 0.0f;
            if constexpr (PASS <= 3) rsum[tid] = 0.0f;
            else { bestL[tid] = 0ull; bestG[tid] = 0ull; }
        }
        __syncthreads();  // S1: zeroing visible
        // stage x chunk (split to bf16 hi/lo) + row sumsq partials
#pragma unroll
        for (int i = 0; i < 6; i++) {
            int f = tid + BLK * i;
            int row = f / 48;
            int col4 = (f - row * 48) * 4;
            float4 v = st[i];
            float ssq = v.x * v.x;
            ssq = fmaf(v.y, v.y, ssq);
            ssq = fmaf(v.z, v.z, ssq);
            ssq = fmaf(v.w, v.w, ssq);
            atomicAdd(&xss[row], ssq);
            uint32_t h0, l0, h1, l1, h2, l2, h3, l3;
            split1(v.x, h0, l0); split1(v.y, h1, l1);
            split1(v.z, h2, l2); split1(v.w, h3, l3);
            uint2 hp = {h0 | (h1 << 16), h2 | (h3 << 16)};
            uint2 lq = {l0 | (l1 << 16), l2 | (l3 << 16)};
            *(uint2*)(xhiS + row * XSTRIDE + col4) = hp;
            *(uint2*)(xloS + row * XSTRIDE + col4) = lq;
        }
        {   // prefetch next chunk while this one computes
            int nc = chunk + gridDim.x;
            if (nc < nchunks) {
                const float4* src = (const float4*)(x + (size_t)nc * CHUNK_ROWS * D_DIM);
#pragma unroll
                for (int i = 0; i < 6; i++) st[i] = src[tid + BLK * i];
            }
        }
        __syncthreads();  // S2: staging visible

        f32x4 E[2][4];
#pragma unroll
        for (int s = 0; s < 4; s++) {
            f32x4 acc0 = {}, acc1 = {};
#pragma unroll
            for (int kk = 0; kk < 6; kk++) {
                int off = (s * 16 + lcol) * XSTRIDE + kk * 32 + quad * 8;
                uint4 hraw = *(const uint4*)(xhiS + off);
                uint4 lraw = *(const uint4*)(xloS + off);
                short8 ah = __builtin_bit_cast(short8, hraw);
                short8 al = __builtin_bit_cast(short8, lraw);
                short8 b0h = __builtin_bit_cast(short8, Bhi[0][kk]);
                short8 b0l = __builtin_bit_cast(short8, Blo[0][kk]);
                short8 b1h = __builtin_bit_cast(short8, Bhi[1][kk]);
                short8 b1l = __builtin_bit_cast(short8, Blo[1][kk]);
                acc0 = __builtin_amdgcn_mfma_f32_16x16x32_bf16(ah, b0h, acc0, 0, 0, 0);
                acc0 = __builtin_amdgcn_mfma_f32_16x16x32_bf16(ah, b0l, acc0, 0, 0, 0);
                acc0 = __builtin_amdgcn_mfma_f32_16x16x32_bf16(al, b0h, acc0, 0, 0, 0);
                acc1 = __builtin_amdgcn_mfma_f32_16x16x32_bf16(ah, b1h, acc1, 0, 0, 0);
                acc1 = __builtin_amdgcn_mfma_f32_16x16x32_bf16(ah, b1l, acc1, 0, 0, 0);
                acc1 = __builtin_amdgcn_mfma_f32_16x16x32_bf16(al, b1h, acc1, 0, 0, 0);
            }
            const int rowb = s * 16 + quad * 4;
            float invnx[4];
#pragma unroll
            for (int r = 0; r < 4; r++) invnx[r] = newton_rsqrt(xss[rowb + r]);
#pragma unroll
            for (int r = 0; r < 4; r++) {
                E[0][s][r] = __expf(acc0[r] * invnx[r] * pnf[0] * 20.0f);
                E[1][s][r] = __expf(acc1[r] * invnx[r] * pnf[1] * 20.0f);
            }
            if constexpr (PASS <= 3) {
#pragma unroll
                for (int r = 0; r < 4; r++) {
                    float p = E[0][s][r] * cf[0] + E[1][s][r] * cf[1];
                    p += __shfl_xor(p, 1);
                    p += __shfl_xor(p, 2);
                    p += __shfl_xor(p, 4);
                    p += __shfl_xor(p, 8);
                    if (lcol == 0) atomicAdd(&rsum[rowb + r], p);
                }
            } else {
#pragma unroll
                for (int r = 0; r < 4; r++) {
                    float v0 = E[0][s][r] * cf[0];
                    float v1 = E[1][s][r] * cf[1];
                    float v; int col;
                    if (v1 > v0) { v = v1; col = c0 + 16 + lcol; }
                    else         { v = v0; col = c0 + lcol; }
                    u64 key = ((u64)__float_as_uint(v) << 32) | (u64)(255 - col);
#pragma unroll
                    for (int m = 1; m <= 8; m <<= 1) {
                        u64 ok = __shfl_xor((unsigned long long)key, m);
                        if (ok > key) key = ok;
                    }
                    if (lcol == 0) {
                        u64* bst = (wave < 4) ? bestL : bestG;
                        atomicMax(&bst[rowb + r], key);
                    }
                }
            }
        }
        __syncthreads();  // S3: rsum / best complete

        if constexpr (PASS <= 3) {
#pragma unroll
            for (int s = 0; s < 4; s++) {
                const int rowb = s * 16 + quad * 4;
#pragma unroll
                for (int r = 0; r < 4; r++) {
                    float rv = fast_rcp(rsum[rowb + r]);
                    colpart[0] = fmaf(E[0][s][r], rv, colpart[0]);
                    colpart[1] = fmaf(E[1][s][r], rv, colpart[1]);
                }
            }
        } else {
            if (tid < CHUNK_ROWS) {
                int colL = 255 - (int)(bestL[tid] & 0xFFFFFFFFull);
                atomicMax(&lastIdx[colL], chunk * CHUNK_ROWS + tid);
            }
#pragma unroll
            for (int rr = 0; rr < 8; rr++) {
                const int row = wave * 8 + rr;
                const int grow = chunk * CHUNK_ROWS + row;
                const int ga = (255 - (int)(bestG[row] & 0xFFFFFFFFull)) - 128;
                const float* gr = gated + ga * D_DIM;
                float v[3];
                float ss = 0.0f;
#pragma unroll
                for (int q = 0; q < 3; q++) {
                    int c = lane + q * 64;
                    float xf = bf2f(xhiS[row * XSTRIDE + c]) + bf2f(xloS[row * XSTRIDE + c]);
                    float vv = 0.5f * (gr[c] + xf);
                    v[q] = vv;
                    ss = fmaf(vv, vv, ss);
                }
                ss += __shfl_xor(ss, 1);
                ss += __shfl_xor(ss, 2);
                ss += __shfl_xor(ss, 4);
                ss += __shfl_xor(ss, 8);
                ss += __shfl_xor(ss, 16);
                ss += __shfl_xor(ss, 32);
                float sc = newton_rsqrt(ss);
                float* orow = outp + (size_t)grow * D_DIM;
#pragma unroll
                for (int q = 0; q < 3; q++) orow[lane + q * 64] = v[q] * sc;
            }
        }
    }

    if constexpr (PASS <= 3) {
#pragma unroll
        for (int t = 0; t < 2; t++) {
            colpart[t] += __shfl_xor(colpart[t], 16);
            colpart[t] += __shfl_xor(colpart[t], 32);
        }
        if (lane < 16) {
            partials[blockIdx.x * KCOLS + c0 + lcol] = colpart[0];
            partials[blockIdx.x * KCOLS + c0 + 16 + lcol] = colpart[1];
        }
    }
}

// ---------------------------------------------------------------------------
__global__ void final_local(const float* __restrict__ lp, const float* __restrict__ x,
                            const int* __restrict__ lastIdx, float* __restrict__ outL) {
    int m = blockIdx.x;   // 128
    int c = threadIdx.x;  // 192
    int idx = lastIdx[m];
    float v = lp[m * D_DIM + c];
    if (idx >= 0) v = 0.96f * v + (float)(1.0 - 0.96) * x[(size_t)idx * D_DIM + c];
    outL[m * D_DIM + c] = v;
}

// ---------------------------------------------------------------------------
extern "C" void kernel_launch(void* const* d_in, const int* in_sizes, int n_in,
                              void* d_out, int out_size, void* d_ws, size_t ws_size,
                              hipStream_t stream) {
    const float* x = (const float*)d_in[0];
    const float* lp = (const float*)d_in[1];
    const float* gp = (const float*)d_in[2];
    const float* W = (const float*)d_in[3];
    const float* b = (const float*)d_in[4];
    float* out = (float*)d_out;
    const int nrows = in_sizes[0] / D_DIM;  // 131072
    const int nchunks = nrows / CHUNK_ROWS; // 2048

    char* wsb = (char*)d_ws;
    float* invnp = (float*)(wsb + 0);
    float* g1 = (float*)(wsb + 1024);
    float* g2 = (float*)(wsb + 2048);
    float* g3 = (float*)(wsb + 3072);
    int* lastIdx = (int*)(wsb + 4096);
    float* gated = (float*)(wsb + 8192);      // 128*192 f
    u16* phi = (u16*)(wsb + 106496);          // 256*192 u16
    u16* plo = (u16*)(wsb + 204800);          // 256*192 u16
    float* partials = (float*)(wsb + 303104); // 256*256 f

    const uint4* phiv = (const uint4*)phi;
    const uint4* plov = (const uint4*)plo;

    prep_kern<<<256, 64, 0, stream>>>(lp, gp, phi, plo, invnp, lastIdx);
    glu_kern<<<128, 384, 0, stream>>>(gp, W, b, gated);
    pass_kern<1><<<GRID_P, BLK, 0, stream>>>(x, phiv, plov, invnp, nullptr, partials,
                                             nullptr, nullptr, nullptr, nchunks);
    reduce_cols<<<1, 256, 0, stream>>>(partials, g1, GRID_P);
    pass_kern<2><<<GRID_P, BLK, 0, stream>>>(x, phiv, plov, invnp, g1, partials,
                                             nullptr, nullptr, nullptr, nchunks);
    reduce_cols<<<1, 256, 0, stream>>>(partials, g2, GRID_P);
    pass_kern<3><<<GRID_P, BLK, 0, stream>>>(x, phiv, plov, invnp, g2, partials,
                                             nullptr, nullptr, nullptr, nchunks);
    reduce_cols<<<1, 256, 0, stream>>>(partials, g3, GRID_P);
    pass_kern<4><<<GRID_P, BLK, 0, stream>>>(x, phiv, plov, invnp, g3, nullptr,
                                             lastIdx, gated, out, nchunks);
    final_local<<<128, 192, 0, stream>>>(lp, x, lastIdx, out + (size_t)nrows * D_DIM);
}